// Round 5
// baseline (270.186 us; speedup 1.0000x reference)
//
#include <hip/hip_runtime.h>
#include <hip/hip_bf16.h>
#include <cstdint>
#include <cstddef>

#define ALPHA 0.2f
#define LOG2E 1.4426950408889634f

using f32x4 = __attribute__((ext_vector_type(4))) float;
using s16x8 = __attribute__((ext_vector_type(8))) short;

__device__ __forceinline__ unsigned f2bf(float f) {
  unsigned u = __float_as_uint(f);
  u = (u + 0x7fffu + ((u >> 16) & 1u)) >> 16;
  return u;
}

// ---------------------------------------------------------------------------
// Kernel 1 (R2 version, verbatim; measured 13.5 us via R4 attribution)
// ---------------------------------------------------------------------------
__global__ __launch_bounds__(256) void k1_proj(
    const float* __restrict__ h, const float* __restrict__ W,
    const float* __restrict__ a1, const float* __restrict__ a2,
    unsigned short* __restrict__ whT, float* __restrict__ s1,
    float* __restrict__ s2) {
  __shared__ __align__(16) float h_lds[64 * 64];           // [n_loc][k]
  __shared__ __align__(16) float W_lds[64 * 64];           // [k][c]
  __shared__ __align__(16) unsigned short t_lds[64 * 64];  // swizzled [c][n]

  const int t = threadIdx.x;
  const int c = t & 63;
  const int w = t >> 6;
  const int row0 = blockIdx.x * 64;

  const float4* hg = (const float4*)(h + (size_t)row0 * 64);
  #pragma unroll
  for (int r = 0; r < 4; ++r) {
    ((float4*)h_lds)[t + r * 256] = hg[t + r * 256];
    ((float4*)W_lds)[t + r * 256] = ((const float4*)W)[t + r * 256];
  }
  const float a1v = a1[c];
  const float a2v = a2[c];
  __syncthreads();

  float acc[16];
  #pragma unroll
  for (int r = 0; r < 16; ++r) acc[r] = 0.0f;

  #pragma unroll 1
  for (int kc = 0; kc < 16; ++kc) {
    const float w0 = W_lds[(kc * 4 + 0) * 64 + c];
    const float w1 = W_lds[(kc * 4 + 1) * 64 + c];
    const float w2 = W_lds[(kc * 4 + 2) * 64 + c];
    const float w3 = W_lds[(kc * 4 + 3) * 64 + c];
    #pragma unroll
    for (int r = 0; r < 16; ++r) {
      const float4 hv = *(const float4*)(h_lds + (w * 16 + r) * 64 + kc * 4);
      acc[r] = fmaf(hv.x, w0, acc[r]);
      acc[r] = fmaf(hv.y, w1, acc[r]);
      acc[r] = fmaf(hv.z, w2, acc[r]);
      acc[r] = fmaf(hv.w, w3, acc[r]);
    }
  }

  #pragma unroll 1
  for (int r = 0; r < 16; ++r) {
    float v1 = acc[r] * a1v;
    float v2 = acc[r] * a2v;
    #pragma unroll
    for (int s = 1; s < 64; s <<= 1) {
      v1 += __shfl_xor(v1, s, 64);
      v2 += __shfl_xor(v2, s, 64);
    }
    if (c == 0) {
      s1[row0 + w * 16 + r] = v1;
      s2[row0 + w * 16 + r] = v2;
    }
  }

  #pragma unroll
  for (int hh = 0; hh < 2; ++hh) {
    uint4 pk;
    pk.x = f2bf(acc[hh * 8 + 0]) | (f2bf(acc[hh * 8 + 1]) << 16);
    pk.y = f2bf(acc[hh * 8 + 2]) | (f2bf(acc[hh * 8 + 3]) << 16);
    pk.z = f2bf(acc[hh * 8 + 4]) | (f2bf(acc[hh * 8 + 5]) << 16);
    pk.w = f2bf(acc[hh * 8 + 6]) | (f2bf(acc[hh * 8 + 7]) << 16);
    const int off = c * 128 + ((w * 32 + hh * 16) ^ ((c & 7) << 4));
    *(uint4*)((char*)t_lds + off) = pk;
  }
  __syncthreads();

  const int b = row0 >> 11;
  const int n0 = row0 & 2047;
  #pragma unroll
  for (int q = 0; q < 2; ++q) {
    const int chunk = q * 256 + t;
    const int cc = chunk >> 3;
    const int w8 = (chunk & 7) * 16;
    const uint4 v =
        *(const uint4*)((const char*)t_lds + cc * 128 + (w8 ^ ((cc & 7) << 4)));
    *(uint4*)((char*)whT + ((size_t)(b * 64 + cc) * 2048 + n0) * 2 + w8) = v;
  }
}

// ---------------------------------------------------------------------------
// Kernel 2 R5: barrier-free free-running waves.
// R4 attribution: k2_v1 = 81 us = 1.8x its 45-us bias-read floor. Cause: the
// per-tile __syncthreads kept all waves phase-aligned (no memory issued during
// compute phases) and the bcur=bnext register copies forced vmcnt(0) per tile.
// Fix: (a) per-wave private whT staging buffer (single-buffered; same-wave DS
// ops are in-order) -> NO barrier in the loop, waves desync and overlap;
// (b) unroll-2 ping-pong bias registers -> every s_waitcnt targets loads
// issued one full iteration earlier. Body order per tile T:
//   [0] ds_write stg(T) (loaded iter T-1)  [1] issue whT(T+1)+bias(T+1)
//   [2] e/softmax with bias(T) regs        [3] rescale + ds_read + MFMA.
// ---------------------------------------------------------------------------
__global__ __launch_bounds__(256) void k2_attn(
    const float* __restrict__ bias, const unsigned short* __restrict__ whT,
    const float* __restrict__ s1g, const float* __restrict__ s2g,
    float* __restrict__ out) {
  __shared__ __align__(16) unsigned short wvbuf[4][4096];  // 8 KB per wave, swz
  __shared__ __align__(16) float s2_lds[2048];

  const int t = threadIdx.x;
  const int lane = t & 63;
  const int w = t >> 6;
  const int arow = lane & 15;  // softmax row within wave's 16
  const int kgrp = lane >> 4;  // 0..3
  const int b = blockIdx.x >> 5;
  const int i0 = (blockIdx.x & 31) * 64;
  const int gi = i0 + w * 16 + arow;

  const float s1v = s1g[b * 2048 + gi];

  #pragma unroll
  for (int q = 0; q < 2; ++q)
    ((float4*)s2_lds)[t + q * 256] =
        ((const float4*)(s2g + b * 2048))[t + q * 256];
  __syncthreads();  // the ONLY barrier: s2_lds visibility

  const char* whT_b = (const char*)whT + (size_t)b * 64 * 2048 * 2;
  const float* bias_p = bias + ((size_t)b * 2048 + gi) * 2048 + kgrp * 8;
  char* mybuf = (char*)wvbuf[w];

  // per-wave staging: 512 x 16B chunks over 64 lanes = 8 per lane.
  // chunk (q, lane): row cc = q*8 + (lane>>3), slot = lane&7 (16B units).
  const int srow = lane >> 3;   // + q*8
  const int sslot = (lane & 7) * 16;

  uint4 stg[8];
  f32x4 biasA[4], biasB[4];

  auto whT_load = [&](int jt) {
    #pragma unroll
    for (int q = 0; q < 8; ++q) {
      const int cc = q * 8 + srow;
      stg[q] = *(const uint4*)(whT_b + (size_t)cc * 4096 + jt * 128 + sslot);
    }
  };
  auto bias_load = [&](f32x4 (&dst)[4], int jt) {
    const float* p = bias_p + jt * 64;
    dst[0] = *(const f32x4*)(p);
    dst[1] = *(const f32x4*)(p + 4);
    dst[2] = *(const f32x4*)(p + 32);
    dst[3] = *(const f32x4*)(p + 36);
  };

  f32x4 acc[4];
  #pragma unroll
  for (int ct = 0; ct < 4; ++ct) acc[ct] = (f32x4){0.f, 0.f, 0.f, 0.f};
  float m = -INFINITY, l = 0.0f;

  // prologue: tile 0 into stg + biasA
  whT_load(0);
  bias_load(biasA, 0);

  auto body = [&](int jt, f32x4 (&bcur)[4], f32x4 (&bnxt)[4]) {
    // [0] write tile jt's staged data (loaded one iteration ago) to own LDS
    #pragma unroll
    for (int q = 0; q < 8; ++q) {
      const int cc = q * 8 + srow;
      *(uint4*)(mybuf + cc * 128 + (sslot ^ ((cc & 7) << 4))) = stg[q];
    }
    // [1] prefetch tile jt+1 (whT -> stg regs, bias -> bnxt regs)
    if (jt < 31) {
      whT_load(jt + 1);
      bias_load(bnxt, jt + 1);
    }

    // [2] e = leakyrelu(s1_i + s2_j) + bias; online softmax (16 vals/lane)
    float ev[16];
    #pragma unroll
    for (int f = 0; f < 2; ++f) {
      const f32x4 sa = *(const f32x4*)(s2_lds + jt * 64 + f * 32 + kgrp * 8);
      const f32x4 sb =
          *(const f32x4*)(s2_lds + jt * 64 + f * 32 + kgrp * 8 + 4);
      const f32x4 ba = bcur[f * 2 + 0];
      const f32x4 bb = bcur[f * 2 + 1];
      #pragma unroll
      for (int e = 0; e < 4; ++e) {
        float x = s1v + sa[e];
        x = x > 0.0f ? x : ALPHA * x;
        ev[f * 8 + e] = x + ba[e];
        float y = s1v + sb[e];
        y = y > 0.0f ? y : ALPHA * y;
        ev[f * 8 + 4 + e] = y + bb[e];
      }
    }

    float mx = ev[0];
    #pragma unroll
    for (int e = 1; e < 16; ++e) mx = fmaxf(mx, ev[e]);
    mx = fmaxf(mx, __shfl_xor(mx, 16, 64));
    mx = fmaxf(mx, __shfl_xor(mx, 32, 64));
    const float mnew = fmaxf(m, mx);
    const float corr = exp2f((m - mnew) * LOG2E);  // m=-inf first iter -> 0

    float ps = 0.0f;
    s16x8 afrag[2];
    #pragma unroll
    for (int f = 0; f < 2; ++f) {
      #pragma unroll
      for (int e = 0; e < 8; ++e) {
        const float p = exp2f((ev[f * 8 + e] - mnew) * LOG2E);
        ps += p;
        afrag[f][e] = (short)f2bf(p);
      }
    }
    ps += __shfl_xor(ps, 16, 64);
    ps += __shfl_xor(ps, 32, 64);
    l = l * corr + ps;
    m = mnew;

    // [3] rescale + PV MFMA (reads own LDS tile written at [0])
    float fc[4];
    #pragma unroll
    for (int r = 0; r < 4; ++r) fc[r] = __shfl(corr, kgrp * 4 + r, 64);
    #pragma unroll
    for (int ct = 0; ct < 4; ++ct) {
      acc[ct][0] *= fc[0];
      acc[ct][1] *= fc[1];
      acc[ct][2] *= fc[2];
      acc[ct][3] *= fc[3];
    }

    #pragma unroll
    for (int ct = 0; ct < 4; ++ct) {
      const int cc = ct * 16 + arow;
      #pragma unroll
      for (int f = 0; f < 2; ++f) {
        const s16x8 bfrag = *(const s16x8*)(
            mybuf + cc * 128 + ((f * 64 + kgrp * 16) ^ ((cc & 7) << 4)));
        asm("s_nop 1\n\t"
            "v_mfma_f32_16x16x32_bf16 %0, %1, %2, %0"
            : "+v"(acc[ct])
            : "v"(afrag[f]), "v"(bfrag));
      }
    }
  };

  #pragma unroll 1
  for (int jt = 0; jt < 32; jt += 2) {
    body(jt + 0, biasA, biasB);
    body(jt + 1, biasB, biasA);
  }

  // MFMA-write -> VALU-read safety margin before epilogue reads of acc
  asm volatile("s_nop 7\n\ts_nop 7" ::: "memory");

  const float linv = 1.0f / l;
  #pragma unroll
  for (int r = 0; r < 4; ++r) {
    const float li = __shfl(linv, kgrp * 4 + r, 64);
    float* op = out + ((size_t)b * 2048 + i0 + w * 16 + kgrp * 4 + r) * 64;
    #pragma unroll
    for (int ct = 0; ct < 4; ++ct) op[ct * 16 + arow] = acc[ct][r] * li;
  }
}

// ---------------------------------------------------------------------------
extern "C" void kernel_launch(void* const* d_in, const int* in_sizes, int n_in,
                              void* d_out, int out_size, void* d_ws,
                              size_t ws_size, hipStream_t stream) {
  const float* h = (const float*)d_in[0];
  const float* bias = (const float*)d_in[1];
  const float* W = (const float*)d_in[2];
  const float* a1 = (const float*)d_in[3];
  const float* a2 = (const float*)d_in[4];
  float* out = (float*)d_out;

  char* ws = (char*)d_ws;
  unsigned short* whT = (unsigned short*)ws;                // 4 MiB
  float* s1 = (float*)(ws + 4 * 1024 * 1024);               // 128 KiB
  float* s2 = (float*)(ws + 4 * 1024 * 1024 + 128 * 1024);  // 128 KiB

  k1_proj<<<dim3(512), dim3(256), 0, stream>>>(h, W, a1, a2, whT, s1, s2);
  k2_attn<<<dim3(512), dim3(256), 0, stream>>>(bias, whT, s1, s2, out);
}

// Round 6
// 87.959 us; speedup vs baseline: 3.0717x; 3.0717x over previous
//
#include <hip/hip_runtime.h>
#include <hip/hip_bf16.h>
#include <cstdint>
#include <cstddef>

#define ALPHA 0.2f
#define LOG2E 1.4426950408889634f

using f32x4 = __attribute__((ext_vector_type(4))) float;
using s16x8 = __attribute__((ext_vector_type(8))) short;

typedef __attribute__((address_space(3))) unsigned lds_u32;
typedef __attribute__((address_space(1))) const unsigned glb_u32;

__device__ __forceinline__ unsigned f2bf(float f) {
  unsigned u = __float_as_uint(f);
  u = (u + 0x7fffu + ((u >> 16) & 1u)) >> 16;
  return u;
}

// ---------------------------------------------------------------------------
// Kernel 1 (R2 version, verbatim; measured 13.5 us via R4 attribution)
// ---------------------------------------------------------------------------
__global__ __launch_bounds__(256) void k1_proj(
    const float* __restrict__ h, const float* __restrict__ W,
    const float* __restrict__ a1, const float* __restrict__ a2,
    unsigned short* __restrict__ whT, float* __restrict__ s1,
    float* __restrict__ s2) {
  __shared__ __align__(16) float h_lds[64 * 64];           // [n_loc][k]
  __shared__ __align__(16) float W_lds[64 * 64];           // [k][c]
  __shared__ __align__(16) unsigned short t_lds[64 * 64];  // swizzled [c][n]

  const int t = threadIdx.x;
  const int c = t & 63;
  const int w = t >> 6;
  const int row0 = blockIdx.x * 64;

  const float4* hg = (const float4*)(h + (size_t)row0 * 64);
  #pragma unroll
  for (int r = 0; r < 4; ++r) {
    ((float4*)h_lds)[t + r * 256] = hg[t + r * 256];
    ((float4*)W_lds)[t + r * 256] = ((const float4*)W)[t + r * 256];
  }
  const float a1v = a1[c];
  const float a2v = a2[c];
  __syncthreads();

  float acc[16];
  #pragma unroll
  for (int r = 0; r < 16; ++r) acc[r] = 0.0f;

  #pragma unroll 1
  for (int kc = 0; kc < 16; ++kc) {
    const float w0 = W_lds[(kc * 4 + 0) * 64 + c];
    const float w1 = W_lds[(kc * 4 + 1) * 64 + c];
    const float w2 = W_lds[(kc * 4 + 2) * 64 + c];
    const float w3 = W_lds[(kc * 4 + 3) * 64 + c];
    #pragma unroll
    for (int r = 0; r < 16; ++r) {
      const float4 hv = *(const float4*)(h_lds + (w * 16 + r) * 64 + kc * 4);
      acc[r] = fmaf(hv.x, w0, acc[r]);
      acc[r] = fmaf(hv.y, w1, acc[r]);
      acc[r] = fmaf(hv.z, w2, acc[r]);
      acc[r] = fmaf(hv.w, w3, acc[r]);
    }
  }

  #pragma unroll 1
  for (int r = 0; r < 16; ++r) {
    float v1 = acc[r] * a1v;
    float v2 = acc[r] * a2v;
    #pragma unroll
    for (int s = 1; s < 64; s <<= 1) {
      v1 += __shfl_xor(v1, s, 64);
      v2 += __shfl_xor(v2, s, 64);
    }
    if (c == 0) {
      s1[row0 + w * 16 + r] = v1;
      s2[row0 + w * 16 + r] = v2;
    }
  }

  #pragma unroll
  for (int hh = 0; hh < 2; ++hh) {
    uint4 pk;
    pk.x = f2bf(acc[hh * 8 + 0]) | (f2bf(acc[hh * 8 + 1]) << 16);
    pk.y = f2bf(acc[hh * 8 + 2]) | (f2bf(acc[hh * 8 + 3]) << 16);
    pk.z = f2bf(acc[hh * 8 + 4]) | (f2bf(acc[hh * 8 + 5]) << 16);
    pk.w = f2bf(acc[hh * 8 + 6]) | (f2bf(acc[hh * 8 + 7]) << 16);
    const int off = c * 128 + ((w * 32 + hh * 16) ^ ((c & 7) << 4));
    *(uint4*)((char*)t_lds + off) = pk;
  }
  __syncthreads();

  const int b = row0 >> 11;
  const int n0 = row0 & 2047;
  #pragma unroll
  for (int q = 0; q < 2; ++q) {
    const int chunk = q * 256 + t;
    const int cc = chunk >> 3;
    const int w8 = (chunk & 7) * 16;
    const uint4 v =
        *(const uint4*)((const char*)t_lds + cc * 128 + (w8 ^ ((cc & 7) << 4)));
    *(uint4*)((char*)whT + ((size_t)(b * 64 + cc) * 2048 + n0) * 2 + w8) = v;
  }
}

// ---------------------------------------------------------------------------
// Kernel 2 R6: barrier-free waves + global_load_lds staging (no stg VGPRs).
// R5 failed from VGPR spill (VGPR=64, 364MB scratch writes): reg-staging
// arrays spilled under the compiler's occupancy-chosen 64-VGPR budget.
// R6: (a) __launch_bounds__(256,2) -> 128 VGPR cap; (b) whT staged via
// __builtin_amdgcn_global_load_lds (width 16) into per-wave DOUBLE-buffered
// LDS (4w x 2 x 8KB + s2 = 72KB, 2 blocks/CU): zero staging regs, no
// stage_write phase. Swizzle rule #21: linear LDS dest + inverse-swizzled
// global source + swizzled ds_read (involution within each 1KB chunk).
// (c) bias ping-pong regs via unroll-2 (no copies). (d) manual
// s_waitcnt vmcnt(12) (steady) / vmcnt(0) (last) before MFMA ds_reads:
// compiler cannot see the gll->ds_read dependency. Same-buffer WAR across
// iterations is safe: prior iteration's MFMAs drained their ds_reads via
// lgkmcnt before this iteration's gll issue.
// ---------------------------------------------------------------------------
__global__ __launch_bounds__(256, 2) void k2_attn(
    const float* __restrict__ bias, const unsigned short* __restrict__ whT,
    const float* __restrict__ s1g, const float* __restrict__ s2g,
    float* __restrict__ out) {
  __shared__ __align__(16) unsigned short wvbuf[4][2][4096];  // per-wave dbuf
  __shared__ __align__(16) float s2_lds[2048];

  const int t = threadIdx.x;
  const int lane = t & 63;
  const int w = t >> 6;
  const int arow = lane & 15;  // softmax row within wave's 16
  const int kgrp = lane >> 4;  // 0..3
  const int b = blockIdx.x >> 5;
  const int i0 = (blockIdx.x & 31) * 64;
  const int gi = i0 + w * 16 + arow;

  const float s1v = s1g[b * 2048 + gi];

  #pragma unroll
  for (int q = 0; q < 2; ++q)
    ((float4*)s2_lds)[t + q * 256] =
        ((const float4*)(s2g + b * 2048))[t + q * 256];
  __syncthreads();  // the ONLY barrier: s2_lds visibility

  const char* whT_b = (const char*)whT + (size_t)b * 64 * 2048 * 2;
  const float* bias_p = bias + ((size_t)b * 2048 + gi) * 2048 + kgrp * 8;

  // gll geometry: one gll moves 1KB = 8 whT rows x 128B. LDS dest linear
  // (lane*16 -> row=lane>>3, slot=lane&7); global source pre-swizzled so a
  // swizzled ds_read sees conflict-free layout. Swizzle: slot16 ^= (row&7)<<4
  // (involution). Per-lane source byte offset within the tile row-block:
  const int src_swz = ((lane & 7) * 16) ^ ((lane >> 3) << 4);
  // per-lane global address for chunk q of tile jt:
  //   whT_b + (q*8 + lane>>3)*4096 + jt*128 + src_swz
  const char* gsrc0 = whT_b + (size_t)(lane >> 3) * 4096 + src_swz;

  f32x4 biasA[4], biasB[4];
  auto bias_load = [&](f32x4 (&dst)[4], int jt) {
    const float* p = bias_p + jt * 64;
    dst[0] = *(const f32x4*)(p);
    dst[1] = *(const f32x4*)(p + 4);
    dst[2] = *(const f32x4*)(p + 32);
    dst[3] = *(const f32x4*)(p + 36);
  };
  auto whT_gll = [&](int jt, int pp) {
    #pragma unroll
    for (int q = 0; q < 8; ++q) {
      __builtin_amdgcn_global_load_lds(
          (glb_u32*)(gsrc0 + (size_t)q * 8 * 4096 + jt * 128),
          (lds_u32*)((char*)wvbuf[w][pp] + q * 1024), 16, 0, 0);
    }
  };

  f32x4 acc[4];
  #pragma unroll
  for (int ct = 0; ct < 4; ++ct) acc[ct] = (f32x4){0.f, 0.f, 0.f, 0.f};
  float m = -INFINITY, l = 0.0f;

  // prologue: tile 0 -> buf0 + biasA
  whT_gll(0, 0);
  bias_load(biasA, 0);

  auto body = [&](int jt, int pp, f32x4 (&bcur)[4], f32x4 (&bnxt)[4]) {
    // [1] prefetch tile jt+1: whT -> other LDS half (gll), bias -> bnxt regs
    if (jt < 31) {
      whT_gll(jt + 1, pp ^ 1);
      bias_load(bnxt, jt + 1);
    }

    // [2] e = leakyrelu(s1_i + s2_j) + bias; online softmax (16 vals/lane)
    float ev[16];
    #pragma unroll
    for (int f = 0; f < 2; ++f) {
      const f32x4 sa = *(const f32x4*)(s2_lds + jt * 64 + f * 32 + kgrp * 8);
      const f32x4 sb =
          *(const f32x4*)(s2_lds + jt * 64 + f * 32 + kgrp * 8 + 4);
      const f32x4 ba = bcur[f * 2 + 0];
      const f32x4 bb = bcur[f * 2 + 1];
      #pragma unroll
      for (int e = 0; e < 4; ++e) {
        float x = s1v + sa[e];
        x = x > 0.0f ? x : ALPHA * x;
        ev[f * 8 + e] = x + ba[e];
        float y = s1v + sb[e];
        y = y > 0.0f ? y : ALPHA * y;
        ev[f * 8 + 4 + e] = y + bb[e];
      }
    }

    float mx = ev[0];
    #pragma unroll
    for (int e = 1; e < 16; ++e) mx = fmaxf(mx, ev[e]);
    mx = fmaxf(mx, __shfl_xor(mx, 16, 64));
    mx = fmaxf(mx, __shfl_xor(mx, 32, 64));
    const float mnew = fmaxf(m, mx);
    const float corr = exp2f((m - mnew) * LOG2E);  // m=-inf first iter -> 0

    float ps = 0.0f;
    s16x8 afrag[2];
    #pragma unroll
    for (int f = 0; f < 2; ++f) {
      #pragma unroll
      for (int e = 0; e < 8; ++e) {
        const float p = exp2f((ev[f * 8 + e] - mnew) * LOG2E);
        ps += p;
        afrag[f][e] = (short)f2bf(p);
      }
    }
    ps += __shfl_xor(ps, 16, 64);
    ps += __shfl_xor(ps, 32, 64);
    l = l * corr + ps;
    m = mnew;

    float fc[4];
    #pragma unroll
    for (int r = 0; r < 4; ++r) fc[r] = __shfl(corr, kgrp * 4 + r, 64);
    #pragma unroll
    for (int ct = 0; ct < 4; ++ct) {
      acc[ct][0] *= fc[0];
      acc[ct][1] *= fc[1];
      acc[ct][2] *= fc[2];
      acc[ct][3] *= fc[3];
    }

    // [3] wait for this tile's gll (issued last iteration), then MFMA.
    // Steady: 12 newer vmem ops (8 gll + 4 bias of jt+1) may remain.
    if (jt < 31)
      asm volatile("s_waitcnt vmcnt(12)" ::: "memory");
    else
      asm volatile("s_waitcnt vmcnt(0)" ::: "memory");

    const char* mybuf = (const char*)wvbuf[w][pp];
    #pragma unroll
    for (int ct = 0; ct < 4; ++ct) {
      const int cc = ct * 16 + arow;
      #pragma unroll
      for (int f = 0; f < 2; ++f) {
        const s16x8 bfrag = *(const s16x8*)(
            mybuf + cc * 128 + ((f * 64 + kgrp * 16) ^ ((cc & 7) << 4)));
        asm("s_nop 1\n\t"
            "v_mfma_f32_16x16x32_bf16 %0, %1, %2, %0"
            : "+v"(acc[ct])
            : "v"(afrag[f]), "v"(bfrag));
      }
    }
  };

  #pragma unroll 1
  for (int jt = 0; jt < 32; jt += 2) {
    body(jt + 0, 0, biasA, biasB);
    body(jt + 1, 1, biasB, biasA);
  }

  // MFMA-write -> VALU-read safety margin before epilogue reads of acc
  asm volatile("s_nop 7\n\ts_nop 7" ::: "memory");

  const float linv = 1.0f / l;
  #pragma unroll
  for (int r = 0; r < 4; ++r) {
    const float li = __shfl(linv, kgrp * 4 + r, 64);
    float* op = out + ((size_t)b * 2048 + i0 + w * 16 + kgrp * 4 + r) * 64;
    #pragma unroll
    for (int ct = 0; ct < 4; ++ct) op[ct * 16 + arow] = acc[ct][r] * li;
  }
}

// ---------------------------------------------------------------------------
extern "C" void kernel_launch(void* const* d_in, const int* in_sizes, int n_in,
                              void* d_out, int out_size, void* d_ws,
                              size_t ws_size, hipStream_t stream) {
  const float* h = (const float*)d_in[0];
  const float* bias = (const float*)d_in[1];
  const float* W = (const float*)d_in[2];
  const float* a1 = (const float*)d_in[3];
  const float* a2 = (const float*)d_in[4];
  float* out = (float*)d_out;

  char* ws = (char*)d_ws;
  unsigned short* whT = (unsigned short*)ws;                // 4 MiB
  float* s1 = (float*)(ws + 4 * 1024 * 1024);               // 128 KiB
  float* s2 = (float*)(ws + 4 * 1024 * 1024 + 128 * 1024);  // 128 KiB

  k1_proj<<<dim3(512), dim3(256), 0, stream>>>(h, W, a1, a2, whT, s1, s2);
  k2_attn<<<dim3(512), dim3(256), 0, stream>>>(bias, whT, s1, s2, out);
}

// Round 7
// 83.068 us; speedup vs baseline: 3.2526x; 1.0589x over previous
//
#include <hip/hip_runtime.h>
#include <hip/hip_bf16.h>
#include <cstdint>
#include <cstddef>

#define ALPHA 0.2f
#define LOG2E 1.4426950408889634f

using f32x4 = __attribute__((ext_vector_type(4))) float;
using s16x8 = __attribute__((ext_vector_type(8))) short;

typedef __attribute__((address_space(3))) unsigned lds_u32;
typedef __attribute__((address_space(1))) const unsigned glb_u32;

__device__ __forceinline__ unsigned f2bf(float f) {
  unsigned u = __float_as_uint(f);
  u = (u + 0x7fffu + ((u >> 16) & 1u)) >> 16;
  return u;
}

// ---------------------------------------------------------------------------
// Kernel 1 (R2 version, verbatim; measured 13.5 us via R4 attribution)
// ---------------------------------------------------------------------------
__global__ __launch_bounds__(256) void k1_proj(
    const float* __restrict__ h, const float* __restrict__ W,
    const float* __restrict__ a1, const float* __restrict__ a2,
    unsigned short* __restrict__ whT, float* __restrict__ s1,
    float* __restrict__ s2) {
  __shared__ __align__(16) float h_lds[64 * 64];           // [n_loc][k]
  __shared__ __align__(16) float W_lds[64 * 64];           // [k][c]
  __shared__ __align__(16) unsigned short t_lds[64 * 64];  // swizzled [c][n]

  const int t = threadIdx.x;
  const int c = t & 63;
  const int w = t >> 6;
  const int row0 = blockIdx.x * 64;

  const float4* hg = (const float4*)(h + (size_t)row0 * 64);
  #pragma unroll
  for (int r = 0; r < 4; ++r) {
    ((float4*)h_lds)[t + r * 256] = hg[t + r * 256];
    ((float4*)W_lds)[t + r * 256] = ((const float4*)W)[t + r * 256];
  }
  const float a1v = a1[c];
  const float a2v = a2[c];
  __syncthreads();

  float acc[16];
  #pragma unroll
  for (int r = 0; r < 16; ++r) acc[r] = 0.0f;

  #pragma unroll 1
  for (int kc = 0; kc < 16; ++kc) {
    const float w0 = W_lds[(kc * 4 + 0) * 64 + c];
    const float w1 = W_lds[(kc * 4 + 1) * 64 + c];
    const float w2 = W_lds[(kc * 4 + 2) * 64 + c];
    const float w3 = W_lds[(kc * 4 + 3) * 64 + c];
    #pragma unroll
    for (int r = 0; r < 16; ++r) {
      const float4 hv = *(const float4*)(h_lds + (w * 16 + r) * 64 + kc * 4);
      acc[r] = fmaf(hv.x, w0, acc[r]);
      acc[r] = fmaf(hv.y, w1, acc[r]);
      acc[r] = fmaf(hv.z, w2, acc[r]);
      acc[r] = fmaf(hv.w, w3, acc[r]);
    }
  }

  #pragma unroll 1
  for (int r = 0; r < 16; ++r) {
    float v1 = acc[r] * a1v;
    float v2 = acc[r] * a2v;
    #pragma unroll
    for (int s = 1; s < 64; s <<= 1) {
      v1 += __shfl_xor(v1, s, 64);
      v2 += __shfl_xor(v2, s, 64);
    }
    if (c == 0) {
      s1[row0 + w * 16 + r] = v1;
      s2[row0 + w * 16 + r] = v2;
    }
  }

  #pragma unroll
  for (int hh = 0; hh < 2; ++hh) {
    uint4 pk;
    pk.x = f2bf(acc[hh * 8 + 0]) | (f2bf(acc[hh * 8 + 1]) << 16);
    pk.y = f2bf(acc[hh * 8 + 2]) | (f2bf(acc[hh * 8 + 3]) << 16);
    pk.z = f2bf(acc[hh * 8 + 4]) | (f2bf(acc[hh * 8 + 5]) << 16);
    pk.w = f2bf(acc[hh * 8 + 6]) | (f2bf(acc[hh * 8 + 7]) << 16);
    const int off = c * 128 + ((w * 32 + hh * 16) ^ ((c & 7) << 4));
    *(uint4*)((char*)t_lds + off) = pk;
  }
  __syncthreads();

  const int b = row0 >> 11;
  const int n0 = row0 & 2047;
  #pragma unroll
  for (int q = 0; q < 2; ++q) {
    const int chunk = q * 256 + t;
    const int cc = chunk >> 3;
    const int w8 = (chunk & 7) * 16;
    const uint4 v =
        *(const uint4*)((const char*)t_lds + cc * 128 + (w8 ^ ((cc & 7) << 4)));
    *(uint4*)((char*)whT + ((size_t)(b * 64 + cc) * 2048 + n0) * 2 + w8) = v;
  }
}

// ---------------------------------------------------------------------------
// Kernel 2 R7: 2-deep pipeline on both streams, block-shared whT.
// v6 (74.5 us = 57% of bias BW) was 1-deep: bias(k) consumed 1 iter after
// issue -> every tile stalls ~HBM latency; and each wave privately glls the
// whole 8KB whT tile (4x traffic).
// R7: (a) block-shared whT, 4-buffer ring (40KB LDS): wave glls only its 2
// chunks; gll(k+2) issued PRE-barrier into buf[(k+2)&3] whose readers
// (MFMA(k-2)) finished two barriers ago -> race-free. (b) raw s_barrier +
// counted vmcnt(12): at the per-tile wait exactly 12 newer ops (gll/bias of
// k+1,k+2) stay in flight; gll(k) is additionally drained by the compiler's
// own bias(k)-read wait (bias(k) issued after gll(k)). Never drains to 0.
// (c) bias 2-deep: bias(k+2) loaded into the reg set freed by bias(k); all
// bias waits target ~2 iterations (>> 900cyc HBM latency). (d) lb(256,2):
// grid gives 2 blocks/CU; let the allocator breathe (no spill).
// ---------------------------------------------------------------------------
__global__ __launch_bounds__(256, 2) void k2_attn(
    const float* __restrict__ bias, const unsigned short* __restrict__ whT,
    const float* __restrict__ s1g, const float* __restrict__ s2g,
    float* __restrict__ out) {
  __shared__ __align__(16) unsigned short wbuf[4][4096];  // 4 x 8KB ring, swz
  __shared__ __align__(16) float s2_lds[2048];

  const int t = threadIdx.x;
  const int lane = t & 63;
  const int w = t >> 6;
  const int arow = lane & 15;  // softmax row within wave's 16
  const int kgrp = lane >> 4;  // 0..3
  const int b = blockIdx.x >> 5;
  const int i0 = (blockIdx.x & 31) * 64;
  const int gi = i0 + w * 16 + arow;

  const float s1v = s1g[b * 2048 + gi];

  #pragma unroll
  for (int q = 0; q < 2; ++q)
    ((float4*)s2_lds)[t + q * 256] =
        ((const float4*)(s2g + b * 2048))[t + q * 256];
  __syncthreads();  // s2_lds visibility (once, before the pipeline fills)

  const char* whT_b = (const char*)whT + (size_t)b * 64 * 2048 * 2;
  const float* bias_p = bias + ((size_t)b * 2048 + gi) * 2048 + kgrp * 8;

  // gll geometry (rule #21): linear LDS dest (uniform base + lane*16),
  // inverse-swizzled per-lane global source, swizzled ds_read. One gll moves
  // 1KB = 8 whT rows x 128B. Wave w owns chunks {2w, 2w+1} -> rows 16w..16w+15.
  const int src_swz = ((lane & 7) * 16) ^ ((lane >> 3) << 4);
  const char* gsrc0 = whT_b + (size_t)(lane >> 3) * 4096 + src_swz;

  auto whT_gll = [&](int jt) {
    char* dst = (char*)wbuf + (jt & 3) * 8192;
    #pragma unroll
    for (int q = 0; q < 2; ++q) {
      const int chunk = w * 2 + q;
      __builtin_amdgcn_global_load_lds(
          (glb_u32*)(gsrc0 + (size_t)chunk * 8 * 4096 + jt * 128),
          (lds_u32*)(dst + chunk * 1024), 16, 0, 0);
    }
  };
  auto bias_load = [&](f32x4 (&dst)[4], int jt) {
    const float* p = bias_p + jt * 64;
    dst[0] = *(const f32x4*)(p);
    dst[1] = *(const f32x4*)(p + 4);
    dst[2] = *(const f32x4*)(p + 32);
    dst[3] = *(const f32x4*)(p + 36);
  };

  f32x4 acc[4];
  #pragma unroll
  for (int ct = 0; ct < 4; ++ct) acc[ct] = (f32x4){0.f, 0.f, 0.f, 0.f};
  float m = -INFINITY, l = 0.0f;

  f32x4 biasA[4], biasB[4];
  // prologue order matters for the vmcnt(12) count: bias(0), gll(0), gll(1),
  // bias(1). (gll(k) older than bias(k) -> the bias(k)-read wait drains it.)
  bias_load(biasA, 0);
  whT_gll(0);
  whT_gll(1);
  bias_load(biasB, 1);

  auto body = [&](int jt, f32x4 (&bcur)[4]) {
    // [A] prefetch whT tile jt+2 -> buf[(jt+2)&3] (its readers, MFMA(jt-2),
    // finished two barriers ago)
    if (jt + 2 < 32) whT_gll(jt + 2);

    // [B] e = leakyrelu(s1_i + s2_j) + bias; online softmax (16 vals/lane)
    float ev[16];
    #pragma unroll
    for (int f = 0; f < 2; ++f) {
      const f32x4 sa = *(const f32x4*)(s2_lds + jt * 64 + f * 32 + kgrp * 8);
      const f32x4 sb =
          *(const f32x4*)(s2_lds + jt * 64 + f * 32 + kgrp * 8 + 4);
      const f32x4 ba = bcur[f * 2 + 0];
      const f32x4 bb = bcur[f * 2 + 1];
      #pragma unroll
      for (int e = 0; e < 4; ++e) {
        float x = s1v + sa[e];
        x = x > 0.0f ? x : ALPHA * x;
        ev[f * 8 + e] = x + ba[e];
        float y = s1v + sb[e];
        y = y > 0.0f ? y : ALPHA * y;
        ev[f * 8 + 4 + e] = y + bb[e];
      }
    }

    float mx = ev[0];
    #pragma unroll
    for (int e = 1; e < 16; ++e) mx = fmaxf(mx, ev[e]);
    mx = fmaxf(mx, __shfl_xor(mx, 16, 64));
    mx = fmaxf(mx, __shfl_xor(mx, 32, 64));
    const float mnew = fmaxf(m, mx);
    const float corr = exp2f((m - mnew) * LOG2E);  // m=-inf first iter -> 0

    float ps = 0.0f;
    s16x8 afrag[2];
    #pragma unroll
    for (int f = 0; f < 2; ++f) {
      #pragma unroll
      for (int e = 0; e < 8; ++e) {
        const float p = exp2f((ev[f * 8 + e] - mnew) * LOG2E);
        ps += p;
        afrag[f][e] = (short)f2bf(p);
      }
    }
    ps += __shfl_xor(ps, 16, 64);
    ps += __shfl_xor(ps, 32, 64);
    l = l * corr + ps;
    m = mnew;

    float fc[4];
    #pragma unroll
    for (int r = 0; r < 4; ++r) fc[r] = __shfl(corr, kgrp * 4 + r, 64);
    #pragma unroll
    for (int ct = 0; ct < 4; ++ct) {
      acc[ct][0] *= fc[0];
      acc[ct][1] *= fc[1];
      acc[ct][2] *= fc[2];
      acc[ct][3] *= fc[3];
    }

    // [A2] prefetch bias tile jt+2 into the reg set just freed by [B]
    if (jt + 2 < 32) bias_load(bcur, jt + 2);

    // [C] ensure own gll(jt) drained. Steady-state queue here is exactly
    // {gll(jt+1), bias(jt+1), gll(jt+2), bias(jt+2)} = 12 -> no-op; at jt=0
    // it drains gll(0). Never waits on the 2-iteration-ahead streams.
    asm volatile("s_waitcnt vmcnt(12)" ::: "memory");
    // [D] all waves' gll(jt) drained -> buf[jt&3] fully valid
    asm volatile("s_barrier" ::: "memory");

    // [F] PV MFMA from the shared tile
    const char* mybuf = (const char*)wbuf + (jt & 3) * 8192;
    #pragma unroll
    for (int ct = 0; ct < 4; ++ct) {
      const int cc = ct * 16 + arow;
      #pragma unroll
      for (int f = 0; f < 2; ++f) {
        const s16x8 bfrag = *(const s16x8*)(
            mybuf + cc * 128 + ((f * 64 + kgrp * 16) ^ ((cc & 7) << 4)));
        asm("s_nop 1\n\t"
            "v_mfma_f32_16x16x32_bf16 %0, %1, %2, %0"
            : "+v"(acc[ct])
            : "v"(afrag[f]), "v"(bfrag));
      }
    }
  };

  #pragma unroll 1
  for (int jt = 0; jt < 32; jt += 2) {
    body(jt + 0, biasA);
    body(jt + 1, biasB);
  }

  // MFMA-write -> VALU-read safety margin before epilogue reads of acc
  asm volatile("s_nop 7\n\ts_nop 7" ::: "memory");

  const float linv = 1.0f / l;
  #pragma unroll
  for (int r = 0; r < 4; ++r) {
    const float li = __shfl(linv, kgrp * 4 + r, 64);
    float* op = out + ((size_t)b * 2048 + i0 + w * 16 + kgrp * 4 + r) * 64;
    #pragma unroll
    for (int ct = 0; ct < 4; ++ct) op[ct * 16 + arow] = acc[ct][r] * li;
  }
}

// ---------------------------------------------------------------------------
extern "C" void kernel_launch(void* const* d_in, const int* in_sizes, int n_in,
                              void* d_out, int out_size, void* d_ws,
                              size_t ws_size, hipStream_t stream) {
  const float* h = (const float*)d_in[0];
  const float* bias = (const float*)d_in[1];
  const float* W = (const float*)d_in[2];
  const float* a1 = (const float*)d_in[3];
  const float* a2 = (const float*)d_in[4];
  float* out = (float*)d_out;

  char* ws = (char*)d_ws;
  unsigned short* whT = (unsigned short*)ws;                // 4 MiB
  float* s1 = (float*)(ws + 4 * 1024 * 1024);               // 128 KiB
  float* s2 = (float*)(ws + 4 * 1024 * 1024 + 128 * 1024);  // 128 KiB

  k1_proj<<<dim3(512), dim3(256), 0, stream>>>(h, W, a1, a2, whT, s1, s2);
  k2_attn<<<dim3(512), dim3(256), 0, stream>>>(bias, whT, s1, s2, out);
}